// Round 6
// baseline (383.250 us; speedup 1.0000x reference)
//
#include <hip/hip_runtime.h>
#include <stdint.h>

// ---------------------------------------------------------------------------
// NIVR: coord-MLP over 512x512 grid.
//   pre_kernel (fused): time branch -> tvec[512]; posenc tables -> Tx,Ty;
//                       W2f -> bf16 frag-swizzled W2s.
//   main: h1 = relu(Tx[x]+Ty[y]+tvec); layer2 via MFMA bf16 16x16x32;
//         fused layer3 epilogue via shuffles. Output [3][N].
//
// R6 changes vs R5 (233us, MfmaUtil 25.6%, VALU 29.4%, 2 blocks/CU but
// phase-locked => A-fill and epilogue serialize with MFMA):
//  - K-loop chunked 4x4 steps; A-fill for chunk c+1 is emitted INSIDE chunk
//    c's compute region (disjoint LDS), so fill VALU/loads of one wave
//    overlap MFMA of sibling waves (m114 co-schedule). Only chunk-0 fill is
//    exposed. 5 barriers total instead of 1 (drain cost ~300cyc each).
//  - pre_kernel W2f swizzle: contiguous reads (one k-row per block),
//    scattered 16B writes (writes don't stall) — was stride-2KB reads.
// ---------------------------------------------------------------------------

typedef short bf16x8 __attribute__((ext_vector_type(8)));
typedef float f32x4 __attribute__((ext_vector_type(4)));

#define PI_F 3.14159265358979323846f
#define SIDE 512
#define NPIX (SIDE * SIDE)

__device__ __forceinline__ unsigned short f2bf(float f) {
  unsigned int u = __float_as_uint(f);
  u += 0x7fffu + ((u >> 16) & 1u);
  return (unsigned short)(u >> 16);
}

// ---------------------------------------------------------------------------
// Fused precompute kernel. Grid = 1025 blocks x 512 threads:
//   blocks 0..511   : posenc tables (v = blockIdx)
//   blocks 512..1023: W2f -> bf16 frag-swizzled W2s (one k-row per block)
//   block 1024      : time branch
// W2s layout: id = ks*16384 + nt*512 + q*128 + ni*8 + j  (shorts)
//   W2s[id] = bf16(W2f[ks*32 + q*8 + j][nt*16 + ni])
// ---------------------------------------------------------------------------
__global__ void pre_kernel(const float* __restrict__ W1p, const float* __restrict__ b1p,
                           const float* __restrict__ W2p, const float* __restrict__ b2p,
                           const float* __restrict__ W1f, const float* __restrict__ b1f,
                           const float* __restrict__ W2f, const int* __restrict__ idx,
                           float* __restrict__ tvec, float* __restrict__ Tx,
                           float* __restrict__ Ty, unsigned short* __restrict__ W2s) {
  __shared__ float sm[256 + 128 + 32];
  const int b = blockIdx.x;
  const int t = threadIdx.x;

  if (b < 512) {
    // ---- posenc tables for coord value v = b ----
    float* enc = sm;  // [20]
    if (t < 10) {
      float u = (float)b / 512.0f;
      float ang = u * ldexpf(PI_F, t);
      enc[t] = sinf(ang);
      enc[10 + t] = cosf(ang);
    }
    __syncthreads();
    float ax = 0.f, ay = 0.f;
#pragma unroll
    for (int l = 0; l < 20; ++l) {
      ax += enc[l] * W1f[l * 512 + t];
      ay += enc[l] * W1f[(20 + l) * 512 + t];
    }
    Tx[b * 512 + t] = ax;
    Ty[b * 512 + t] = ay;
  } else if (b < 1024) {
    // ---- W2f -> bf16 swizzle: k-row = b-512, n = t (contiguous read) ----
    const int k = b - 512, n = t;
    const int ks = k >> 5, q = (k >> 3) & 3, j = k & 7;
    const int nt = n >> 4, ni = n & 15;
    W2s[ks * 16384 + nt * 512 + q * 128 + ni * 8 + j] = f2bf(W2f[k * 512 + n]);
  } else {
    // ---- time branch ----
    float* r_s = sm;           // [32]
    float* h_s = sm + 32;      // [256]
    float* phi_s = sm + 288;   // [128]
    const float tt = (float)idx[0] / 300.0f;
    if (t < 16) {
      float ang = tt * ldexpf(PI_F, t);
      r_s[t] = sinf(ang);
      r_s[16 + t] = cosf(ang);
    }
    __syncthreads();
    if (t < 256) {
      float a = b1p[t];
#pragma unroll
      for (int i = 0; i < 32; ++i) a += r_s[i] * W1p[i * 256 + t];
      h_s[t] = fmaxf(a, 0.f);
    }
    __syncthreads();
    if (t < 128) {
      float a = b2p[t];
      for (int i = 0; i < 256; ++i) a += h_s[i] * W2p[i * 128 + t];
      phi_s[t] = a;
    }
    __syncthreads();
    {
      float a = b1f[t];
      for (int p = 0; p < 128; ++p) a += phi_s[p] * W1f[(40 + p) * 512 + t];
      tvec[t] = a;
    }
  }
}

// ---------------------------------------------------------------------------
// Main fused kernel. Block = 512 thr (8 waves), BM=64, BN=512,
// K=512 in 16 steps of 32, chunked 4x4. Wave w owns N-slice [w*64, w*64+64).
// LDS: A tile 64KB (frag-swizzled) + part 6KB -> 2 blocks/CU.
// ---------------------------------------------------------------------------
__global__ __launch_bounds__(512, 2) void main_kernel(
    const float* __restrict__ Tx, const float* __restrict__ Ty,
    const float* __restrict__ tvec, const unsigned short* __restrict__ W2s,
    const float* __restrict__ b2f, const float* __restrict__ W3f,
    const float* __restrict__ b3f, float* __restrict__ out) {
  __shared__ __attribute__((aligned(16))) unsigned short Ab[16 * 2048];  // 64KB
  __shared__ float part[8][64][3];                                       // 6KB

  const int t = threadIdx.x;
  const int w = t >> 6;            // wave id 0..7  (N-slice)
  const int lane = t & 63;
  const int q = lane >> 4;
  const int lr = lane & 15;
  const int x0 = blockIdx.x * 8, y0 = blockIdx.y * 8;

  // per-wave B pointer: fragment slab (ks, nt) is 512 shorts (1KB);
  // wave w owns nt-slots w*4..w*4+3; lane reads at +lane*8 (16B).
  const unsigned short* bptr = W2s + (w * 4) * 512 + lane * 8;

  // ---- A-fill thread mapping: slot v = t&255 -> (mt,q2,mr); group g = t>>8
  // covers slabs ks = 4c + g and 4c + g + 2 for chunk c.
  const int v = t & 255, g = t >> 8;
  const int p = ((v >> 6) << 4) + (v & 15);
  const int q2 = (v >> 4) & 3;
  const int xi = x0 + (p >> 3), yi = y0 + (p & 7);
  const float* txp = Tx + xi * 512 + q2 * 8;
  const float* typ = Ty + yi * 512 + q2 * 8;
  const float* tvp = tvec + q2 * 8;
  unsigned short* aw = &Ab[v * 8];

  auto fill_slab = [&](int ks) {
    const int ko = ks * 32;
    float4 a0 = *(const float4*)(txp + ko);
    float4 a1 = *(const float4*)(txp + ko + 4);
    float4 b0 = *(const float4*)(typ + ko);
    float4 b1 = *(const float4*)(typ + ko + 4);
    float4 c0 = *(const float4*)(tvp + ko);
    float4 c1 = *(const float4*)(tvp + ko + 4);
    uint4 pk;
    pk.x = (unsigned)f2bf(fmaxf(a0.x + b0.x + c0.x, 0.f)) |
           ((unsigned)f2bf(fmaxf(a0.y + b0.y + c0.y, 0.f)) << 16);
    pk.y = (unsigned)f2bf(fmaxf(a0.z + b0.z + c0.z, 0.f)) |
           ((unsigned)f2bf(fmaxf(a0.w + b0.w + c0.w, 0.f)) << 16);
    pk.z = (unsigned)f2bf(fmaxf(a1.x + b1.x + c1.x, 0.f)) |
           ((unsigned)f2bf(fmaxf(a1.y + b1.y + c1.y, 0.f)) << 16);
    pk.w = (unsigned)f2bf(fmaxf(a1.z + b1.z + c1.z, 0.f)) |
           ((unsigned)f2bf(fmaxf(a1.w + b1.w + c1.w, 0.f)) << 16);
    *(uint4*)(aw + ks * 2048) = pk;
  };

  // ---- B(0) prefetch, then fill chunk 0 ----
  bf16x8 bcur[4], bnxt[4];
#pragma unroll
  for (int nt = 0; nt < 4; ++nt)
    bcur[nt] = *(const bf16x8*)(bptr + nt * 512);

  fill_slab(g);
  fill_slab(g + 2);

  f32x4 acc[4][4];
#pragma unroll
  for (int i = 0; i < 4; ++i)
#pragma unroll
    for (int j2 = 0; j2 < 4; ++j2) acc[i][j2] = (f32x4){0.f, 0.f, 0.f, 0.f};

  __syncthreads();

  // ---- chunked K-loop: fill chunk c+1 overlaps MFMA of chunk c ----
#pragma unroll
  for (int c = 0; c < 4; ++c) {
    if (c < 3) {
      fill_slab(4 * (c + 1) + g);
      fill_slab(4 * (c + 1) + g + 2);
    }
#pragma unroll
    for (int s2 = 0; s2 < 4; ++s2) {
      const int ks = 4 * c + s2;
      if (ks < 15) {
#pragma unroll
        for (int nt = 0; nt < 4; ++nt)
          bnxt[nt] = *(const bf16x8*)(bptr + (ks + 1) * 16384 + nt * 512);
      }
      bf16x8 af[4];
#pragma unroll
      for (int mt = 0; mt < 4; ++mt)
        af[mt] = *(const bf16x8*)&Ab[ks * 2048 + mt * 512 + lane * 8];
#pragma unroll
      for (int nt = 0; nt < 4; ++nt)
#pragma unroll
        for (int mt = 0; mt < 4; ++mt)
          acc[mt][nt] =
              __builtin_amdgcn_mfma_f32_16x16x32_bf16(af[mt], bcur[nt], acc[mt][nt], 0, 0, 0);
#pragma unroll
      for (int nt = 0; nt < 4; ++nt) bcur[nt] = bnxt[nt];
    }
    __syncthreads();
  }

  // ---- epilogue: h2 = relu(acc + b2f); rgb partial = h2 @ W3f (k-slice) ----
  float w3v[4][3];
  float bb2[4];
#pragma unroll
  for (int nt = 0; nt < 4; ++nt) {
    const int k = w * 64 + nt * 16 + lr;
    bb2[nt] = b2f[k];
    w3v[nt][0] = W3f[k * 3 + 0];
    w3v[nt][1] = W3f[k * 3 + 1];
    w3v[nt][2] = W3f[k * 3 + 2];
  }
#pragma unroll
  for (int half = 0; half < 2; ++half) {
    float vv[2][4][3];
#pragma unroll
    for (int mi = 0; mi < 2; ++mi)
#pragma unroll
      for (int r = 0; r < 4; ++r)
#pragma unroll
        for (int cc = 0; cc < 3; ++cc) vv[mi][r][cc] = 0.f;
#pragma unroll
    for (int mi = 0; mi < 2; ++mi) {
      const int mt = half * 2 + mi;
#pragma unroll
      for (int r = 0; r < 4; ++r) {
#pragma unroll
        for (int nt = 0; nt < 4; ++nt) {
          float h2 = fmaxf(acc[mt][nt][r] + bb2[nt], 0.f);
          vv[mi][r][0] += h2 * w3v[nt][0];
          vv[mi][r][1] += h2 * w3v[nt][1];
          vv[mi][r][2] += h2 * w3v[nt][2];
        }
      }
    }
#pragma unroll
    for (int d = 1; d < 16; d <<= 1) {
#pragma unroll
      for (int mi = 0; mi < 2; ++mi)
#pragma unroll
        for (int r = 0; r < 4; ++r)
#pragma unroll
          for (int cc = 0; cc < 3; ++cc)
            vv[mi][r][cc] += __shfl_xor(vv[mi][r][cc], d, 64);
    }
    if (lr == 0) {
#pragma unroll
      for (int mi = 0; mi < 2; ++mi)
#pragma unroll
        for (int r = 0; r < 4; ++r) {
          const int row = (half * 2 + mi) * 16 + q * 4 + r;
#pragma unroll
          for (int cc = 0; cc < 3; ++cc) part[w][row][cc] = vv[mi][r][cc];
        }
    }
  }
  __syncthreads();
  if (t < 192) {
    const int c = t >> 6, mm = t & 63;
    float sum = b3f[c];
#pragma unroll
    for (int ww = 0; ww < 8; ++ww) sum += part[ww][mm][c];
    const int n = (x0 + (mm >> 3)) * 512 + (y0 + (mm & 7));
    out[c * NPIX + n] = sum;
  }
}

// ---------------------------------------------------------------------------
// Inputs: 0 coords (unused), 1 W1p, 2 b1p, 3 W2p, 4 b2p, 5 W1f, 6 b1f,
//         7 W2f, 8 b2f, 9 W3f, 10 b3f, 11 idx
// ---------------------------------------------------------------------------
extern "C" void kernel_launch(void* const* d_in, const int* in_sizes, int n_in,
                              void* d_out, int out_size, void* d_ws, size_t ws_size,
                              hipStream_t stream) {
  const float* W1p = (const float*)d_in[1];
  const float* b1p = (const float*)d_in[2];
  const float* W2p = (const float*)d_in[3];
  const float* b2p = (const float*)d_in[4];
  const float* W1f = (const float*)d_in[5];
  const float* b1f = (const float*)d_in[6];
  const float* W2f = (const float*)d_in[7];
  const float* b2f = (const float*)d_in[8];
  const float* W3f = (const float*)d_in[9];
  const float* b3f = (const float*)d_in[10];
  const int* idx = (const int*)d_in[11];
  float* out = (float*)d_out;

  char* ws = (char*)d_ws;
  float* Tx = (float*)ws;                                   // 1 MB
  float* Ty = (float*)(ws + (1u << 20));                    // 1 MB
  float* tvec = (float*)(ws + (2u << 20));                  // 2 KB
  unsigned short* W2s = (unsigned short*)(ws + (2u << 20) + 8192);  // 512 KB

  hipLaunchKernelGGL(pre_kernel, dim3(1025), dim3(512), 0, stream,
                     W1p, b1p, W2p, b2p, W1f, b1f, W2f, idx, tvec, Tx, Ty, W2s);
  hipLaunchKernelGGL(main_kernel, dim3(64, 64), dim3(512), 0, stream,
                     Tx, Ty, tvec, W2s, b2f, W3f, b3f, out);
}

// Round 7
// 344.267 us; speedup vs baseline: 1.1132x; 1.1132x over previous
//
#include <hip/hip_runtime.h>
#include <stdint.h>

// ---------------------------------------------------------------------------
// NIVR: coord-MLP over 512x512 grid.
//   pre_kernel: posenc tables with time-branch folded in -> Txp (=Tx+tvec), Ty
//               (time branch recomputed redundantly per block, fp32-exact);
//               W2f -> bf16 frag-swizzled W2s.
//   main: h1 = relu(Txp[x]+Ty[y]); layer2 via MFMA bf16 16x16x32;
//         fused layer3 epilogue via shuffles. Output [3][N].
//
// R7 vs R5/R6: R2/R4/R5 all ~235us regardless of structure => L2-BW-bound on
// B (2.1GB; each 64-px block re-reads all 512KB of W2s; eff ~9TB/s).
//  - BM=128 (wave tile m=8,n=4, acc=128 AGPR, launch_bounds(512,2)):
//    B traffic halves to 1.05GB. 2048 blocks.
//  - A tile 128KB -> 4 chunks x 4 K-steps, LDS dbuf 2x32KB, software-
//    pipelined RIGHT (R6 lesson: DS ops are in-order per wave, so ds_writes
//    must come AFTER the chunk's MFMAs; loads issue one step ahead).
//  - tvec folded into Tx by pre_kernel => fill is 4 float4 loads per slab.
// ---------------------------------------------------------------------------

typedef short bf16x8 __attribute__((ext_vector_type(8)));
typedef float f32x4 __attribute__((ext_vector_type(4)));

#define PI_F 3.14159265358979323846f
#define SIDE 512
#define NPIX (SIDE * SIDE)

__device__ __forceinline__ unsigned short f2bf(float f) {
  unsigned int u = __float_as_uint(f);
  u += 0x7fffu + ((u >> 16) & 1u);
  return (unsigned short)(u >> 16);
}

// ---------------------------------------------------------------------------
// Fused precompute kernel. Grid = 1024 blocks x 512 threads:
//   blocks 0..511  : posenc tables for coord v=b, with time branch folded:
//                    Txp[v][k] = tvec[k] + sum_l enc[l] W1f[l][k]
//                    Ty [v][k] =           sum_l enc[l] W1f[20+l][k]
//                    tvec[k] = b1f[k] + phi_t @ W1f[40:168][k] (recomputed
//                    redundantly per block; deterministic fp32)
//   blocks 512..1023: W2f -> bf16 frag-swizzled W2s (k-row = b-512)
// W2s layout: id = ks*16384 + nt*512 + q*128 + ni*8 + j  (shorts)
//   W2s[id] = bf16(W2f[ks*32 + q*8 + j][nt*16 + ni])
// ---------------------------------------------------------------------------
__global__ void pre_kernel(const float* __restrict__ W1p, const float* __restrict__ b1p,
                           const float* __restrict__ W2p, const float* __restrict__ b2p,
                           const float* __restrict__ W1f, const float* __restrict__ b1f,
                           const float* __restrict__ W2f, const int* __restrict__ idx,
                           float* __restrict__ Txp, float* __restrict__ Ty,
                           unsigned short* __restrict__ W2s) {
  const int b = blockIdx.x;
  const int t = threadIdx.x;

  if (b >= 512) {
    // ---- W2f -> bf16 swizzle: k-row = b-512, n = t (contiguous read) ----
    const int k = b - 512, n = t;
    const int ks = k >> 5, q = (k >> 3) & 3, j = k & 7;
    const int nt = n >> 4, ni = n & 15;
    W2s[ks * 16384 + nt * 512 + q * 128 + ni * 8 + j] = f2bf(W2f[k * 512 + n]);
    return;
  }

  __shared__ float enc[20];
  __shared__ float r_s[32];
  __shared__ float h_s[256];
  __shared__ float phi_s[128];

  if (t < 10) {
    float u = (float)b / 512.0f;
    float ang = u * ldexpf(PI_F, t);
    enc[t] = sinf(ang);
    enc[10 + t] = cosf(ang);
  }
  if (t >= 32 && t < 48) {
    const int l = t - 32;
    float tt = (float)idx[0] / 300.0f;
    float ang = tt * ldexpf(PI_F, l);
    r_s[l] = sinf(ang);
    r_s[16 + l] = cosf(ang);
  }
  __syncthreads();
  if (t < 256) {
    float a = b1p[t];
#pragma unroll
    for (int i = 0; i < 32; ++i) a += r_s[i] * W1p[i * 256 + t];
    h_s[t] = fmaxf(a, 0.f);
  }
  __syncthreads();
  if (t < 128) {
    float a = b2p[t];
    for (int i = 0; i < 256; ++i) a += h_s[i] * W2p[i * 128 + t];
    phi_s[t] = a;
  }
  __syncthreads();
  {
    float tv = b1f[t];
    for (int p = 0; p < 128; ++p) tv += phi_s[p] * W1f[(40 + p) * 512 + t];
    float ax = tv, ay = 0.f;
#pragma unroll
    for (int l = 0; l < 20; ++l) {
      ax += enc[l] * W1f[l * 512 + t];
      ay += enc[l] * W1f[(20 + l) * 512 + t];
    }
    Txp[b * 512 + t] = ax;
    Ty[b * 512 + t] = ay;
  }
}

// ---------------------------------------------------------------------------
// Main fused kernel. Block = 512 thr (8 waves), BM=128 (16x8 patch), BN=512,
// K=512 in 4 chunks x 4 steps of 32. Wave w owns N-slice [w*64, w*64+64),
// tile m=8 (all 128 px), n=4. acc = 8x4 f32x4 = 128 AGPR.
// LDS: A chunk dbuf 2x32KB + part 12KB = 76KB. launch_bounds(512,2).
// ---------------------------------------------------------------------------
__global__ __launch_bounds__(512, 2) void main_kernel(
    const float* __restrict__ Txp, const float* __restrict__ Ty,
    const unsigned short* __restrict__ W2s, const float* __restrict__ b2f,
    const float* __restrict__ W3f, const float* __restrict__ b3f,
    float* __restrict__ out) {
  __shared__ __attribute__((aligned(16))) unsigned short Ab[2][16384];  // 2x32KB
  __shared__ float part[8][128][3];                                     // 12KB

  const int t = threadIdx.x;
  const int w = t >> 6;            // wave id 0..7  (N-slice)
  const int lane = t & 63;
  const int q = lane >> 4;
  const int lr = lane & 15;
  const int x0 = blockIdx.x * 16, y0 = blockIdx.y * 8;

  // B: wave w owns nt-slots w*4..w*4+3; frag (ks,nt) at +ks*16384 + nt*512.
  const unsigned short* bptr = W2s + (w * 4) * 512 + lane * 8;

  bf16x8 bcur[4], bnxt[4];
#pragma unroll
  for (int nt = 0; nt < 4; ++nt)
    bcur[nt] = *(const bf16x8*)(bptr + nt * 512);

  // ---- A-fill mapping: slot v = t: mt=v>>6, q2=(v>>4)&3, mr=v&15;
  // pixel p = mt*16+mr; thread covers k = step*32 + q2*8 .. +7.
  const int v = t;
  const int p = ((v >> 6) << 4) + (v & 15);
  const int q2 = (v >> 4) & 3;
  const int xi = x0 + (p >> 3), yi = y0 + (p & 7);
  const float* txp = Txp + xi * 512 + q2 * 8;
  const float* typ = Ty + yi * 512 + q2 * 8;

  struct Fill { float4 a0, a1, b0, b1; };
  auto fload = [&](int ks) -> Fill {
    const int ko = ks * 32;
    Fill f;
    f.a0 = *(const float4*)(txp + ko);
    f.a1 = *(const float4*)(txp + ko + 4);
    f.b0 = *(const float4*)(typ + ko);
    f.b1 = *(const float4*)(typ + ko + 4);
    return f;
  };
  auto fstore = [&](const Fill& f, int buf, int s2) {
    uint4 pk;
    pk.x = (unsigned)f2bf(fmaxf(f.a0.x + f.b0.x, 0.f)) |
           ((unsigned)f2bf(fmaxf(f.a0.y + f.b0.y, 0.f)) << 16);
    pk.y = (unsigned)f2bf(fmaxf(f.a0.z + f.b0.z, 0.f)) |
           ((unsigned)f2bf(fmaxf(f.a0.w + f.b0.w, 0.f)) << 16);
    pk.z = (unsigned)f2bf(fmaxf(f.a1.x + f.b1.x, 0.f)) |
           ((unsigned)f2bf(fmaxf(f.a1.y + f.b1.y, 0.f)) << 16);
    pk.w = (unsigned)f2bf(fmaxf(f.a1.z + f.b1.z, 0.f)) |
           ((unsigned)f2bf(fmaxf(f.a1.w + f.b1.w, 0.f)) << 16);
    *(uint4*)&Ab[buf][s2 * 4096 + v * 8] = pk;
  };

  f32x4 acc[8][4];
#pragma unroll
  for (int i = 0; i < 8; ++i)
#pragma unroll
    for (int j2 = 0; j2 < 4; ++j2) acc[i][j2] = (f32x4){0.f, 0.f, 0.f, 0.f};

  // ---- prologue: fill chunk 0 into buf 0 (loads batched, then packed) ----
  {
    Fill f0 = fload(0), f1 = fload(1), f2 = fload(2), f3 = fload(3);
    fstore(f0, 0, 0);
    fstore(f1, 0, 1);
    fstore(f2, 0, 2);
    fstore(f3, 0, 3);
  }
  __syncthreads();

  // MFMA step: m=8 (af pair-loaded), n=4.
  auto mfma_step = [&](int buf, int s2, bf16x8 (&bb)[4]) {
    const int abase = s2 * 4096 + lane * 8;
#pragma unroll
    for (int mtp = 0; mtp < 4; ++mtp) {
      bf16x8 af0 = *(const bf16x8*)&Ab[buf][abase + (mtp * 2) * 512];
      bf16x8 af1 = *(const bf16x8*)&Ab[buf][abase + (mtp * 2 + 1) * 512];
#pragma unroll
      for (int nt = 0; nt < 4; ++nt) {
        acc[mtp * 2][nt] =
            __builtin_amdgcn_mfma_f32_16x16x32_bf16(af0, bb[nt], acc[mtp * 2][nt], 0, 0, 0);
        acc[mtp * 2 + 1][nt] =
            __builtin_amdgcn_mfma_f32_16x16x32_bf16(af1, bb[nt], acc[mtp * 2 + 1][nt], 0, 0, 0);
      }
    }
  };

  // ---- chunked K-loop. Per chunk c: loads for chunk c+1 issue one step
  // ahead; ds_writes AFTER each step's MFMAs (DS is in-order per wave).
#pragma unroll
  for (int c = 0; c < 4; ++c) {
    const int cb = c & 1, nb = cb ^ 1;
    Fill f[2];
    if (c < 3) f[0] = fload(4 * (c + 1));
#pragma unroll
    for (int s2 = 0; s2 < 4; ++s2) {
      const int ks = 4 * c + s2;
      if (c < 3 && s2 < 3) f[(s2 + 1) & 1] = fload(4 * (c + 1) + s2 + 1);
      if (ks < 15) {
#pragma unroll
        for (int nt = 0; nt < 4; ++nt)
          bnxt[nt] = *(const bf16x8*)(bptr + (ks + 1) * 16384 + nt * 512);
      }
      mfma_step(cb, s2, bcur);
      if (c < 3) fstore(f[s2 & 1], nb, s2);
#pragma unroll
      for (int nt = 0; nt < 4; ++nt) bcur[nt] = bnxt[nt];
    }
    if (c < 3) __syncthreads();
  }

  // ---- epilogue: h2 = relu(acc + b2f); rgb partial = h2 @ W3f (k-slice) ----
  float w3v[4][3];
  float bb2[4];
#pragma unroll
  for (int nt = 0; nt < 4; ++nt) {
    const int k = w * 64 + nt * 16 + lr;
    bb2[nt] = b2f[k];
    w3v[nt][0] = W3f[k * 3 + 0];
    w3v[nt][1] = W3f[k * 3 + 1];
    w3v[nt][2] = W3f[k * 3 + 2];
  }
#pragma unroll
  for (int mtq = 0; mtq < 4; ++mtq) {
    float vv[2][4][3];
#pragma unroll
    for (int mi = 0; mi < 2; ++mi)
#pragma unroll
      for (int r = 0; r < 4; ++r)
#pragma unroll
        for (int cc = 0; cc < 3; ++cc) vv[mi][r][cc] = 0.f;
#pragma unroll
    for (int mi = 0; mi < 2; ++mi) {
      const int mt = mtq * 2 + mi;
#pragma unroll
      for (int r = 0; r < 4; ++r) {
#pragma unroll
        for (int nt = 0; nt < 4; ++nt) {
          float h2 = fmaxf(acc[mt][nt][r] + bb2[nt], 0.f);
          vv[mi][r][0] += h2 * w3v[nt][0];
          vv[mi][r][1] += h2 * w3v[nt][1];
          vv[mi][r][2] += h2 * w3v[nt][2];
        }
      }
    }
#pragma unroll
    for (int d = 1; d < 16; d <<= 1) {
#pragma unroll
      for (int mi = 0; mi < 2; ++mi)
#pragma unroll
        for (int r = 0; r < 4; ++r)
#pragma unroll
          for (int cc = 0; cc < 3; ++cc)
            vv[mi][r][cc] += __shfl_xor(vv[mi][r][cc], d, 64);
    }
    if (lr == 0) {
#pragma unroll
      for (int mi = 0; mi < 2; ++mi)
#pragma unroll
        for (int r = 0; r < 4; ++r) {
          const int row = (mtq * 2 + mi) * 16 + q * 4 + r;
#pragma unroll
          for (int cc = 0; cc < 3; ++cc) part[w][row][cc] = vv[mi][r][cc];
        }
    }
  }
  __syncthreads();
  if (t < 384) {
    const int c = t >> 7, mm = t & 127;
    float sum = b3f[c];
#pragma unroll
    for (int ww = 0; ww < 8; ++ww) sum += part[ww][mm][c];
    const int n = (x0 + (mm >> 3)) * 512 + (y0 + (mm & 7));
    out[c * NPIX + n] = sum;
  }
}

// ---------------------------------------------------------------------------
// Inputs: 0 coords (unused), 1 W1p, 2 b1p, 3 W2p, 4 b2p, 5 W1f, 6 b1f,
//         7 W2f, 8 b2f, 9 W3f, 10 b3f, 11 idx
// ---------------------------------------------------------------------------
extern "C" void kernel_launch(void* const* d_in, const int* in_sizes, int n_in,
                              void* d_out, int out_size, void* d_ws, size_t ws_size,
                              hipStream_t stream) {
  const float* W1p = (const float*)d_in[1];
  const float* b1p = (const float*)d_in[2];
  const float* W2p = (const float*)d_in[3];
  const float* b2p = (const float*)d_in[4];
  const float* W1f = (const float*)d_in[5];
  const float* b1f = (const float*)d_in[6];
  const float* W2f = (const float*)d_in[7];
  const float* b2f = (const float*)d_in[8];
  const float* W3f = (const float*)d_in[9];
  const float* b3f = (const float*)d_in[10];
  const int* idx = (const int*)d_in[11];
  float* out = (float*)d_out;

  char* ws = (char*)d_ws;
  float* Txp = (float*)ws;                                  // 1 MB
  float* Ty = (float*)(ws + (1u << 20));                    // 1 MB
  unsigned short* W2s = (unsigned short*)(ws + (2u << 20));  // 512 KB

  hipLaunchKernelGGL(pre_kernel, dim3(1024), dim3(512), 0, stream,
                     W1p, b1p, W2p, b2p, W1f, b1f, W2f, idx, Txp, Ty, W2s);
  hipLaunchKernelGGL(main_kernel, dim3(32, 64), dim3(512), 0, stream,
                     Txp, Ty, W2s, b2f, W3f, b3f, out);
}

// Round 8
// 301.305 us; speedup vs baseline: 1.2720x; 1.1426x over previous
//
#include <hip/hip_runtime.h>
#include <stdint.h>

// ---------------------------------------------------------------------------
// NIVR: coord-MLP over 512x512 grid.
//   pre_kernel: posenc tables with time-branch folded in -> Txp (=Tx+tvec), Ty
//               (time branch recomputed redundantly per block, fp32-exact);
//               W2f -> bf16 frag-swizzled W2s.
//   main: h1 = relu(Txp[x]+Ty[y]); layer2 via MFMA bf16 16x16x32;
//         fused layer3 epilogue via shuffles. Output [3][N].
//
// R8 vs R7 (281us, spilled: VGPR=128=cap, WRITE 130MB): same BM=128 tile,
// register-disciplined so the spill disappears and the B-traffic-halving
// hypothesis gets a clean test.
//  - Single Fill buffer (16 regs, was 32): fload(chunk c+1, slab s) just
//    before mfma_step(s) (~155cyc MFMA covers L2 latency), fstore after
//    (DS in-order, R6 lesson).
//  - Chunk loop rolled (#pragma unroll 1) to cap scheduler pressure.
//  - Live set est: 128 AGPR + 16 bcur + 16 bnxt + 16 f + 8 af + ~25 misc
//    = ~209 < 256 budget.
// ---------------------------------------------------------------------------

typedef short bf16x8 __attribute__((ext_vector_type(8)));
typedef float f32x4 __attribute__((ext_vector_type(4)));

#define PI_F 3.14159265358979323846f
#define SIDE 512
#define NPIX (SIDE * SIDE)

__device__ __forceinline__ unsigned short f2bf(float f) {
  unsigned int u = __float_as_uint(f);
  u += 0x7fffu + ((u >> 16) & 1u);
  return (unsigned short)(u >> 16);
}

// ---------------------------------------------------------------------------
// Fused precompute kernel. Grid = 1024 blocks x 512 threads:
//   blocks 0..511  : posenc tables for coord v=b, time branch folded:
//                    Txp[v][k] = tvec[k] + sum_l enc[l] W1f[l][k]
//                    Ty [v][k] =           sum_l enc[l] W1f[20+l][k]
//   blocks 512..1023: W2f -> bf16 frag-swizzled W2s (k-row = b-512)
// W2s layout: id = ks*16384 + nt*512 + q*128 + ni*8 + j  (shorts)
//   W2s[id] = bf16(W2f[ks*32 + q*8 + j][nt*16 + ni])
// ---------------------------------------------------------------------------
__global__ void pre_kernel(const float* __restrict__ W1p, const float* __restrict__ b1p,
                           const float* __restrict__ W2p, const float* __restrict__ b2p,
                           const float* __restrict__ W1f, const float* __restrict__ b1f,
                           const float* __restrict__ W2f, const int* __restrict__ idx,
                           float* __restrict__ Txp, float* __restrict__ Ty,
                           unsigned short* __restrict__ W2s) {
  const int b = blockIdx.x;
  const int t = threadIdx.x;

  if (b >= 512) {
    const int k = b - 512, n = t;
    const int ks = k >> 5, q = (k >> 3) & 3, j = k & 7;
    const int nt = n >> 4, ni = n & 15;
    W2s[ks * 16384 + nt * 512 + q * 128 + ni * 8 + j] = f2bf(W2f[k * 512 + n]);
    return;
  }

  __shared__ float enc[20];
  __shared__ float r_s[32];
  __shared__ float h_s[256];
  __shared__ float phi_s[128];

  if (t < 10) {
    float u = (float)b / 512.0f;
    float ang = u * ldexpf(PI_F, t);
    enc[t] = sinf(ang);
    enc[10 + t] = cosf(ang);
  }
  if (t >= 32 && t < 48) {
    const int l = t - 32;
    float tt = (float)idx[0] / 300.0f;
    float ang = tt * ldexpf(PI_F, l);
    r_s[l] = sinf(ang);
    r_s[16 + l] = cosf(ang);
  }
  __syncthreads();
  if (t < 256) {
    float a = b1p[t];
#pragma unroll
    for (int i = 0; i < 32; ++i) a += r_s[i] * W1p[i * 256 + t];
    h_s[t] = fmaxf(a, 0.f);
  }
  __syncthreads();
  if (t < 128) {
    float a = b2p[t];
    for (int i = 0; i < 256; ++i) a += h_s[i] * W2p[i * 128 + t];
    phi_s[t] = a;
  }
  __syncthreads();
  {
    float tv = b1f[t];
    for (int p = 0; p < 128; ++p) tv += phi_s[p] * W1f[(40 + p) * 512 + t];
    float ax = tv, ay = 0.f;
#pragma unroll
    for (int l = 0; l < 20; ++l) {
      ax += enc[l] * W1f[l * 512 + t];
      ay += enc[l] * W1f[(20 + l) * 512 + t];
    }
    Txp[b * 512 + t] = ax;
    Ty[b * 512 + t] = ay;
  }
}

// ---------------------------------------------------------------------------
// Main fused kernel. Block = 512 thr (8 waves), BM=128 (16x8 patch), BN=512,
// K=512 in 4 chunks x 4 steps of 32. Wave w owns N-slice [w*64, w*64+64),
// tile m=8, n=4. acc = 8x4 f32x4 = 128 AGPR.
// LDS: A chunk dbuf 2x32KB + part 12KB = 76KB -> 2 blocks/CU.
// ---------------------------------------------------------------------------
__global__ __launch_bounds__(512, 2) void main_kernel(
    const float* __restrict__ Txp, const float* __restrict__ Ty,
    const unsigned short* __restrict__ W2s, const float* __restrict__ b2f,
    const float* __restrict__ W3f, const float* __restrict__ b3f,
    float* __restrict__ out) {
  __shared__ __attribute__((aligned(16))) unsigned short Ab[2][16384];  // 2x32KB
  __shared__ float part[8][128][3];                                     // 12KB

  const int t = threadIdx.x;
  const int w = t >> 6;            // wave id 0..7  (N-slice)
  const int lane = t & 63;
  const int q = lane >> 4;
  const int lr = lane & 15;
  const int x0 = blockIdx.x * 16, y0 = blockIdx.y * 8;

  // B: wave w owns nt-slots w*4..w*4+3; frag (ks,nt) at +ks*16384 + nt*512.
  const unsigned short* bptr = W2s + (w * 4) * 512 + lane * 8;

  bf16x8 bcur[4], bnxt[4];
#pragma unroll
  for (int nt = 0; nt < 4; ++nt)
    bcur[nt] = *(const bf16x8*)(bptr + nt * 512);

  // ---- A-fill mapping: slot v = t: mt=v>>6, q2=(v>>4)&3, mr=v&15;
  // pixel p = mt*16+mr; thread covers k = step*32 + q2*8 .. +7.
  const int v = t;
  const int p = ((v >> 6) << 4) + (v & 15);
  const int q2 = (v >> 4) & 3;
  const int xi = x0 + (p >> 3), yi = y0 + (p & 7);
  const float* txp = Txp + xi * 512 + q2 * 8;
  const float* typ = Ty + yi * 512 + q2 * 8;

  struct Fill { float4 a0, a1, b0, b1; };
  auto fload = [&](int ks) -> Fill {
    const int ko = ks * 32;
    Fill f;
    f.a0 = *(const float4*)(txp + ko);
    f.a1 = *(const float4*)(txp + ko + 4);
    f.b0 = *(const float4*)(typ + ko);
    f.b1 = *(const float4*)(typ + ko + 4);
    return f;
  };
  auto fstore = [&](const Fill& f, int buf, int s2) {
    uint4 pk;
    pk.x = (unsigned)f2bf(fmaxf(f.a0.x + f.b0.x, 0.f)) |
           ((unsigned)f2bf(fmaxf(f.a0.y + f.b0.y, 0.f)) << 16);
    pk.y = (unsigned)f2bf(fmaxf(f.a0.z + f.b0.z, 0.f)) |
           ((unsigned)f2bf(fmaxf(f.a0.w + f.b0.w, 0.f)) << 16);
    pk.z = (unsigned)f2bf(fmaxf(f.a1.x + f.b1.x, 0.f)) |
           ((unsigned)f2bf(fmaxf(f.a1.y + f.b1.y, 0.f)) << 16);
    pk.w = (unsigned)f2bf(fmaxf(f.a1.z + f.b1.z, 0.f)) |
           ((unsigned)f2bf(fmaxf(f.a1.w + f.b1.w, 0.f)) << 16);
    *(uint4*)&Ab[buf][s2 * 4096 + v * 8] = pk;
  };

  f32x4 acc[8][4];
#pragma unroll
  for (int i = 0; i < 8; ++i)
#pragma unroll
    for (int j2 = 0; j2 < 4; ++j2) acc[i][j2] = (f32x4){0.f, 0.f, 0.f, 0.f};

  // ---- prologue: fill chunk 0 into buf 0 ----
  {
    Fill f0 = fload(0), f1 = fload(1), f2 = fload(2), f3 = fload(3);
    fstore(f0, 0, 0);
    fstore(f1, 0, 1);
    fstore(f2, 0, 2);
    fstore(f3, 0, 3);
  }
  __syncthreads();

  // MFMA step: m=8 (af pair-loaded), n=4.
  auto mfma_step = [&](int buf, int s2, bf16x8 (&bb)[4]) {
    const int abase = s2 * 4096 + lane * 8;
#pragma unroll
    for (int mtp = 0; mtp < 4; ++mtp) {
      bf16x8 af0 = *(const bf16x8*)&Ab[buf][abase + (mtp * 2) * 512];
      bf16x8 af1 = *(const bf16x8*)&Ab[buf][abase + (mtp * 2 + 1) * 512];
#pragma unroll
      for (int nt = 0; nt < 4; ++nt) {
        acc[mtp * 2][nt] =
            __builtin_amdgcn_mfma_f32_16x16x32_bf16(af0, bb[nt], acc[mtp * 2][nt], 0, 0, 0);
        acc[mtp * 2 + 1][nt] =
            __builtin_amdgcn_mfma_f32_16x16x32_bf16(af1, bb[nt], acc[mtp * 2 + 1][nt], 0, 0, 0);
      }
    }
  };

  // ---- chunked K-loop (rolled): per step s2 of chunk c:
  //   fload(chunk c+1, slab s2)  [latency covered by this step's MFMAs]
  //   B prefetch for ks+1 into bnxt
  //   mfma_step(cb, s2, bcur)
  //   fstore -> other buffer     [DS in-order: after this step's ds_reads]
#pragma unroll 1
  for (int c = 0; c < 4; ++c) {
    const int cb = c & 1, nb = cb ^ 1;
#pragma unroll
    for (int s2 = 0; s2 < 4; ++s2) {
      const int ks = 4 * c + s2;
      Fill f;
      if (c < 3) f = fload(4 * (c + 1) + s2);
      if (ks < 15) {
#pragma unroll
        for (int nt = 0; nt < 4; ++nt)
          bnxt[nt] = *(const bf16x8*)(bptr + (ks + 1) * 16384 + nt * 512);
      }
      mfma_step(cb, s2, bcur);
      if (c < 3) fstore(f, nb, s2);
#pragma unroll
      for (int nt = 0; nt < 4; ++nt) bcur[nt] = bnxt[nt];
    }
    if (c < 3) __syncthreads();
  }

  // ---- epilogue: h2 = relu(acc + b2f); rgb partial = h2 @ W3f (k-slice) ----
  float w3v[4][3];
  float bb2[4];
#pragma unroll
  for (int nt = 0; nt < 4; ++nt) {
    const int k = w * 64 + nt * 16 + lr;
    bb2[nt] = b2f[k];
    w3v[nt][0] = W3f[k * 3 + 0];
    w3v[nt][1] = W3f[k * 3 + 1];
    w3v[nt][2] = W3f[k * 3 + 2];
  }
#pragma unroll
  for (int mtq = 0; mtq < 4; ++mtq) {
    float vv[2][4][3];
#pragma unroll
    for (int mi = 0; mi < 2; ++mi)
#pragma unroll
      for (int r = 0; r < 4; ++r)
#pragma unroll
        for (int cc = 0; cc < 3; ++cc) vv[mi][r][cc] = 0.f;
#pragma unroll
    for (int mi = 0; mi < 2; ++mi) {
      const int mt = mtq * 2 + mi;
#pragma unroll
      for (int r = 0; r < 4; ++r) {
#pragma unroll
        for (int nt = 0; nt < 4; ++nt) {
          float h2 = fmaxf(acc[mt][nt][r] + bb2[nt], 0.f);
          vv[mi][r][0] += h2 * w3v[nt][0];
          vv[mi][r][1] += h2 * w3v[nt][1];
          vv[mi][r][2] += h2 * w3v[nt][2];
        }
      }
    }
#pragma unroll
    for (int d = 1; d < 16; d <<= 1) {
#pragma unroll
      for (int mi = 0; mi < 2; ++mi)
#pragma unroll
        for (int r = 0; r < 4; ++r)
#pragma unroll
          for (int cc = 0; cc < 3; ++cc)
            vv[mi][r][cc] += __shfl_xor(vv[mi][r][cc], d, 64);
    }
    if (lr == 0) {
#pragma unroll
      for (int mi = 0; mi < 2; ++mi)
#pragma unroll
        for (int r = 0; r < 4; ++r) {
          const int row = (mtq * 2 + mi) * 16 + q * 4 + r;
#pragma unroll
          for (int cc = 0; cc < 3; ++cc) part[w][row][cc] = vv[mi][r][cc];
        }
    }
  }
  __syncthreads();
  if (t < 384) {
    const int c = t >> 7, mm = t & 127;
    float sum = b3f[c];
#pragma unroll
    for (int ww = 0; ww < 8; ++ww) sum += part[ww][mm][c];
    const int n = (x0 + (mm >> 3)) * 512 + (y0 + (mm & 7));
    out[c * NPIX + n] = sum;
  }
}

// ---------------------------------------------------------------------------
// Inputs: 0 coords (unused), 1 W1p, 2 b1p, 3 W2p, 4 b2p, 5 W1f, 6 b1f,
//         7 W2f, 8 b2f, 9 W3f, 10 b3f, 11 idx
// ---------------------------------------------------------------------------
extern "C" void kernel_launch(void* const* d_in, const int* in_sizes, int n_in,
                              void* d_out, int out_size, void* d_ws, size_t ws_size,
                              hipStream_t stream) {
  const float* W1p = (const float*)d_in[1];
  const float* b1p = (const float*)d_in[2];
  const float* W2p = (const float*)d_in[3];
  const float* b2p = (const float*)d_in[4];
  const float* W1f = (const float*)d_in[5];
  const float* b1f = (const float*)d_in[6];
  const float* W2f = (const float*)d_in[7];
  const float* b2f = (const float*)d_in[8];
  const float* W3f = (const float*)d_in[9];
  const float* b3f = (const float*)d_in[10];
  const int* idx = (const int*)d_in[11];
  float* out = (float*)d_out;

  char* ws = (char*)d_ws;
  float* Txp = (float*)ws;                                   // 1 MB
  float* Ty = (float*)(ws + (1u << 20));                     // 1 MB
  unsigned short* W2s = (unsigned short*)(ws + (2u << 20));  // 512 KB

  hipLaunchKernelGGL(pre_kernel, dim3(1024), dim3(512), 0, stream,
                     W1p, b1p, W2p, b2p, W1f, b1f, W2f, idx, Txp, Ty, W2s);
  hipLaunchKernelGGL(main_kernel, dim3(32, 64), dim3(512), 0, stream,
                     Txp, Ty, W2s, b2f, W3f, b3f, out);
}

// Round 9
// 290.655 us; speedup vs baseline: 1.3186x; 1.0366x over previous
//
#include <hip/hip_runtime.h>
#include <stdint.h>

// ---------------------------------------------------------------------------
// NIVR: coord-MLP over 512x512 grid.
//   pre_kernel: posenc tables, time branch folded -> Txp (=Tx+tvec), Ty;
//               W2f -> bf16 frag-swizzled W2s.
//   main: h1 = relu(Txp[x]+Ty[y]); layer2 via MFMA bf16 16x16x32;
//         fused layer3 epilogue via shuffles. Output [3][N].
//
// R9 vs R8: R2/R4/R5/R8 all ~234us (MfmaUtil ~25%) across four different
// structures => not L2-BW, not spills, not conflicts. Cycle accounting:
// wave-step wall ~1100cyc vs 310cyc matrix work => ~800cyc/step per-wave
// dependency stalls (B prefetch only 1 step deep; bcur=bnxt copies force
// vmcnt waits in the producing step; af ds_reads issued at use).
// R9 = R5 structure + explicit depth-2/depth-1 software pipeline:
//  - breg[3][4] rotation: B loads for step ks+2 issued at step ks, no copies.
//  - areg[2][4] rotation: af ds_reads for step ks+1 issued before step ks's
//    MFMAs (A static in LDS => no DS-order hazard).
//  - tvec folded into Txp (R8 pre_kernel): fill = 2 float4 loads/slab.
// Live set: 64 AGPR acc + 48 breg + 32 areg + ~30 misc ~ 175 < 256 @ (512,2).
// ---------------------------------------------------------------------------

typedef short bf16x8 __attribute__((ext_vector_type(8)));
typedef float f32x4 __attribute__((ext_vector_type(4)));

#define PI_F 3.14159265358979323846f
#define SIDE 512
#define NPIX (SIDE * SIDE)

__device__ __forceinline__ unsigned short f2bf(float f) {
  unsigned int u = __float_as_uint(f);
  u += 0x7fffu + ((u >> 16) & 1u);
  return (unsigned short)(u >> 16);
}

// ---------------------------------------------------------------------------
// Fused precompute kernel. Grid = 1024 blocks x 512 threads:
//   blocks 0..511  : posenc tables for coord v=b, time branch folded:
//                    Txp[v][k] = tvec[k] + sum_l enc[l] W1f[l][k]
//                    Ty [v][k] =           sum_l enc[l] W1f[20+l][k]
//   blocks 512..1023: W2f -> bf16 frag-swizzled W2s (k-row = b-512)
// W2s layout: id = ks*16384 + nt*512 + q*128 + ni*8 + j  (shorts)
//   W2s[id] = bf16(W2f[ks*32 + q*8 + j][nt*16 + ni])
// ---------------------------------------------------------------------------
__global__ void pre_kernel(const float* __restrict__ W1p, const float* __restrict__ b1p,
                           const float* __restrict__ W2p, const float* __restrict__ b2p,
                           const float* __restrict__ W1f, const float* __restrict__ b1f,
                           const float* __restrict__ W2f, const int* __restrict__ idx,
                           float* __restrict__ Txp, float* __restrict__ Ty,
                           unsigned short* __restrict__ W2s) {
  const int b = blockIdx.x;
  const int t = threadIdx.x;

  if (b >= 512) {
    const int k = b - 512, n = t;
    const int ks = k >> 5, q = (k >> 3) & 3, j = k & 7;
    const int nt = n >> 4, ni = n & 15;
    W2s[ks * 16384 + nt * 512 + q * 128 + ni * 8 + j] = f2bf(W2f[k * 512 + n]);
    return;
  }

  __shared__ float enc[20];
  __shared__ float r_s[32];
  __shared__ float h_s[256];
  __shared__ float phi_s[128];

  if (t < 10) {
    float u = (float)b / 512.0f;
    float ang = u * ldexpf(PI_F, t);
    enc[t] = sinf(ang);
    enc[10 + t] = cosf(ang);
  }
  if (t >= 32 && t < 48) {
    const int l = t - 32;
    float tt = (float)idx[0] / 300.0f;
    float ang = tt * ldexpf(PI_F, l);
    r_s[l] = sinf(ang);
    r_s[16 + l] = cosf(ang);
  }
  __syncthreads();
  if (t < 256) {
    float a = b1p[t];
#pragma unroll
    for (int i = 0; i < 32; ++i) a += r_s[i] * W1p[i * 256 + t];
    h_s[t] = fmaxf(a, 0.f);
  }
  __syncthreads();
  if (t < 128) {
    float a = b2p[t];
    for (int i = 0; i < 256; ++i) a += h_s[i] * W2p[i * 128 + t];
    phi_s[t] = a;
  }
  __syncthreads();
  {
    float tv = b1f[t];
    for (int p = 0; p < 128; ++p) tv += phi_s[p] * W1f[(40 + p) * 512 + t];
    float ax = tv, ay = 0.f;
#pragma unroll
    for (int l = 0; l < 20; ++l) {
      ax += enc[l] * W1f[l * 512 + t];
      ay += enc[l] * W1f[(20 + l) * 512 + t];
    }
    Txp[b * 512 + t] = ax;
    Ty[b * 512 + t] = ay;
  }
}

// ---------------------------------------------------------------------------
// Main fused kernel. Block = 512 thr (8 waves), BM=64 (8x8 patch), BN=512,
// K=512 in 16 steps of 32. Wave w owns N-slice [w*64, w*64+64).
// A tile 64KB resident in LDS (filled once); B via depth-2 register pipeline.
// ---------------------------------------------------------------------------
__global__ __launch_bounds__(512, 2) void main_kernel(
    const float* __restrict__ Txp, const float* __restrict__ Ty,
    const unsigned short* __restrict__ W2s, const float* __restrict__ b2f,
    const float* __restrict__ W3f, const float* __restrict__ b3f,
    float* __restrict__ out) {
  __shared__ __attribute__((aligned(16))) unsigned short Ab[16 * 2048];  // 64KB
  __shared__ float part[8][64][3];                                       // 6KB

  const int t = threadIdx.x;
  const int w = t >> 6;            // wave id 0..7  (N-slice)
  const int lane = t & 63;
  const int q = lane >> 4;
  const int lr = lane & 15;
  const int x0 = blockIdx.x * 8, y0 = blockIdx.y * 8;

  // B: wave w owns nt-slots w*4..w*4+3; frag (ks,nt) at +ks*16384 + nt*512;
  // lane reads at +lane*8 (16B, coalesced 1KB/wave).
  const unsigned short* bptr = W2s + (w * 4) * 512 + lane * 8;

  // ---- B pipeline: depth 2. breg[ks%3] used at step ks. ----
  bf16x8 breg[3][4];
#pragma unroll
  for (int nt = 0; nt < 4; ++nt) {
    breg[0][nt] = *(const bf16x8*)(bptr + 0 * 16384 + nt * 512);
    breg[1][nt] = *(const bf16x8*)(bptr + 1 * 16384 + nt * 512);
  }

  // ---- A fill (once): thread (p = t>>3, s = t&7) covers pixel p,
  // k = ks*32 + s*4..+3; frag slot abase, conflict-free (R5-verified).
  {
    const int p = t >> 3, s = t & 7;
    const int xi = x0 + (p >> 3), yi = y0 + (p & 7);
    const float* txp = Txp + xi * 512 + s * 4;
    const float* typ = Ty + yi * 512 + s * 4;
    const int abase = (((p >> 4) * 4 + (s >> 1)) * 16 + (p & 15)) * 8 + (s & 1) * 4;
#pragma unroll
    for (int ks = 0; ks < 16; ++ks) {
      float4 a = *(const float4*)(txp + ks * 32);
      float4 b = *(const float4*)(typ + ks * 32);
      uint2 pk;
      pk.x = (unsigned)f2bf(fmaxf(a.x + b.x, 0.f)) |
             ((unsigned)f2bf(fmaxf(a.y + b.y, 0.f)) << 16);
      pk.y = (unsigned)f2bf(fmaxf(a.z + b.z, 0.f)) |
             ((unsigned)f2bf(fmaxf(a.w + b.w, 0.f)) << 16);
      *(uint2*)&Ab[ks * 2048 + abase] = pk;
    }
  }

  f32x4 acc[4][4];
#pragma unroll
  for (int i = 0; i < 4; ++i)
#pragma unroll
    for (int j2 = 0; j2 < 4; ++j2) acc[i][j2] = (f32x4){0.f, 0.f, 0.f, 0.f};

  __syncthreads();  // publishes A; the only barrier before the epilogue

  // ---- A-frag pipeline: depth 1. areg[ks&1] used at step ks. ----
  bf16x8 areg[2][4];
#pragma unroll
  for (int mt = 0; mt < 4; ++mt)
    areg[0][mt] = *(const bf16x8*)&Ab[0 * 2048 + mt * 512 + lane * 8];

  // ---- K-loop, fully unrolled, no barriers, no register copies ----
#pragma unroll
  for (int ks = 0; ks < 16; ++ks) {
    // B loads for step ks+2 (depth 2: ~2 step-walls of latency cover)
    if (ks + 2 < 16) {
#pragma unroll
      for (int nt = 0; nt < 4; ++nt)
        breg[(ks + 2) % 3][nt] =
            *(const bf16x8*)(bptr + (ks + 2) * 16384 + nt * 512);
    }
    // A-frag ds_reads for step ks+1 (issued before this step's MFMAs)
    if (ks + 1 < 16) {
#pragma unroll
      for (int mt = 0; mt < 4; ++mt)
        areg[(ks + 1) & 1][mt] =
            *(const bf16x8*)&Ab[(ks + 1) * 2048 + mt * 512 + lane * 8];
    }
    // MFMAs for step ks
#pragma unroll
    for (int nt = 0; nt < 4; ++nt)
#pragma unroll
      for (int mt = 0; mt < 4; ++mt)
        acc[mt][nt] = __builtin_amdgcn_mfma_f32_16x16x32_bf16(
            areg[ks & 1][mt], breg[ks % 3][nt], acc[mt][nt], 0, 0, 0);
  }

  // ---- epilogue: h2 = relu(acc + b2f); rgb partial = h2 @ W3f (k-slice) ----
  float w3v[4][3];
  float bb2[4];
#pragma unroll
  for (int nt = 0; nt < 4; ++nt) {
    const int k = w * 64 + nt * 16 + lr;
    bb2[nt] = b2f[k];
    w3v[nt][0] = W3f[k * 3 + 0];
    w3v[nt][1] = W3f[k * 3 + 1];
    w3v[nt][2] = W3f[k * 3 + 2];
  }
#pragma unroll
  for (int half = 0; half < 2; ++half) {
    float vv[2][4][3];
#pragma unroll
    for (int mi = 0; mi < 2; ++mi)
#pragma unroll
      for (int r = 0; r < 4; ++r)
#pragma unroll
        for (int cc = 0; cc < 3; ++cc) vv[mi][r][cc] = 0.f;
#pragma unroll
    for (int mi = 0; mi < 2; ++mi) {
      const int mt = half * 2 + mi;
#pragma unroll
      for (int r = 0; r < 4; ++r) {
#pragma unroll
        for (int nt = 0; nt < 4; ++nt) {
          float h2 = fmaxf(acc[mt][nt][r] + bb2[nt], 0.f);
          vv[mi][r][0] += h2 * w3v[nt][0];
          vv[mi][r][1] += h2 * w3v[nt][1];
          vv[mi][r][2] += h2 * w3v[nt][2];
        }
      }
    }
#pragma unroll
    for (int d = 1; d < 16; d <<= 1) {
#pragma unroll
      for (int mi = 0; mi < 2; ++mi)
#pragma unroll
        for (int r = 0; r < 4; ++r)
#pragma unroll
          for (int cc = 0; cc < 3; ++cc)
            vv[mi][r][cc] += __shfl_xor(vv[mi][r][cc], d, 64);
    }
    if (lr == 0) {
#pragma unroll
      for (int mi = 0; mi < 2; ++mi)
#pragma unroll
        for (int r = 0; r < 4; ++r) {
          const int row = (half * 2 + mi) * 16 + q * 4 + r;
#pragma unroll
          for (int cc = 0; cc < 3; ++cc) part[w][row][cc] = vv[mi][r][cc];
        }
    }
  }
  __syncthreads();
  if (t < 192) {
    const int c = t >> 6, mm = t & 63;
    float sum = b3f[c];
#pragma unroll
    for (int ww = 0; ww < 8; ++ww) sum += part[ww][mm][c];
    const int n = (x0 + (mm >> 3)) * 512 + (y0 + (mm & 7));
    out[c * NPIX + n] = sum;
  }
}

// ---------------------------------------------------------------------------
// Inputs: 0 coords (unused), 1 W1p, 2 b1p, 3 W2p, 4 b2p, 5 W1f, 6 b1f,
//         7 W2f, 8 b2f, 9 W3f, 10 b3f, 11 idx
// ---------------------------------------------------------------------------
extern "C" void kernel_launch(void* const* d_in, const int* in_sizes, int n_in,
                              void* d_out, int out_size, void* d_ws, size_t ws_size,
                              hipStream_t stream) {
  const float* W1p = (const float*)d_in[1];
  const float* b1p = (const float*)d_in[2];
  const float* W2p = (const float*)d_in[3];
  const float* b2p = (const float*)d_in[4];
  const float* W1f = (const float*)d_in[5];
  const float* b1f = (const float*)d_in[6];
  const float* W2f = (const float*)d_in[7];
  const float* b2f = (const float*)d_in[8];
  const float* W3f = (const float*)d_in[9];
  const float* b3f = (const float*)d_in[10];
  const int* idx = (const int*)d_in[11];
  float* out = (float*)d_out;

  char* ws = (char*)d_ws;
  float* Txp = (float*)ws;                                   // 1 MB
  float* Ty = (float*)(ws + (1u << 20));                     // 1 MB
  unsigned short* W2s = (unsigned short*)(ws + (2u << 20));  // 512 KB

  hipLaunchKernelGGL(pre_kernel, dim3(1024), dim3(512), 0, stream,
                     W1p, b1p, W2p, b2p, W1f, b1f, W2f, idx, Txp, Ty, W2s);
  hipLaunchKernelGGL(main_kernel, dim3(64, 64), dim3(512), 0, stream,
                     Txp, Ty, W2s, b2f, W3f, b3f, out);
}